// Round 1
// baseline (6584.730 us; speedup 1.0000x reference)
//
#include <hip/hip_runtime.h>
#include <cstdint>
#include <cstddef>

#define T_TOK 4096
#define DIM   768
#define VOCAB 32000
#define NLAYER 4
#define HALF_TV 65536000u   // T*V/2

typedef short bf16x8 __attribute__((ext_vector_type(8)));
typedef float f32x4  __attribute__((ext_vector_type(4)));

// ---------------- threefry2x32 (exact JAX semantics) ----------------
__host__ __device__ inline void tf2x32(uint32_t k0, uint32_t k1, uint32_t& v0, uint32_t& v1){
  uint32_t ks2 = k0 ^ k1 ^ 0x1BD11BDAu;
  uint32_t x0 = v0 + k0, x1 = v1 + k1;
#define TFR(R) { x0 += x1; x1 = (x1<<R)|(x1>>(32-R)); x1 ^= x0; }
  TFR(13) TFR(15) TFR(26) TFR(6)
  x0 += k1;  x1 += ks2 + 1u;
  TFR(17) TFR(29) TFR(16) TFR(24)
  x0 += ks2; x1 += k0 + 2u;
  TFR(13) TFR(15) TFR(26) TFR(6)
  x0 += k0;  x1 += k1 + 3u;
  TFR(17) TFR(29) TFR(16) TFR(24)
  x0 += k1;  x1 += ks2 + 4u;
  TFR(13) TFR(15) TFR(26) TFR(6)
  x0 += ks2; x1 += k0 + 5u;
#undef TFR
  v0 = x0; v1 = x1;
}

// gumbel for flat index t*V+v under folded key (kf0,kf1), matching
// jax.random.categorical's uniform(minval=tiny)->-log(-log(u)) path.
__device__ inline float gumbel_tv(uint32_t kf0, uint32_t kf1, uint32_t t, uint32_t v){
  uint32_t m = t * (uint32_t)VOCAB + v;
  uint32_t x0, x1;
  bool hi = (m >= HALF_TV);
  if (hi) { x0 = m - HALF_TV; x1 = m; } else { x0 = m; x1 = m + HALF_TV; }
  tf2x32(kf0, kf1, x0, x1);
  uint32_t bits = hi ? x1 : x0;
  uint32_t k = bits >> 9;
  float u = k ? (float)k * 1.1920928955078125e-7f   // k * 2^-23 (exact)
              : 1.17549435082228751e-38f;            // FLT_MIN (u==0 -> tiny)
  return -logf(-logf(u));
}

// ---------------- helpers ----------------
__device__ inline unsigned short f2bf(float f){  // RNE f32->bf16
  uint32_t u = __float_as_uint(f);
  return (unsigned short)((u + 0x7FFFu + ((u >> 16) & 1u)) >> 16);
}
__device__ inline void cvt8(const float* f, bool lo, unsigned short* out){
  #pragma unroll
  for (int e=0;e<8;e++){
    float x = f[e];
    unsigned short h = f2bf(x);
    if (lo){
      float hf = __uint_as_float(((uint32_t)h) << 16);
      h = f2bf(x - hf);
    }
    out[e] = h;
  }
}
__device__ inline float blockReduceSum(float v){
  __shared__ float red[4];
  #pragma unroll
  for (int off=32; off>0; off>>=1) v += __shfl_down(v, off);
  int w = threadIdx.x >> 6;
  __syncthreads();
  if ((threadIdx.x & 63) == 0) red[w] = v;
  __syncthreads();
  return red[0] + red[1] + red[2] + red[3];
}

// ---------------- GEMM: C[M,N] = A[M,K] @ B[K,N]  (f32 in/out, bf16 MFMA) ----
// NSEG=1: plain bf16.  NSEG=3: split-bf16 (hi*hi + lo*hi + hi*lo), f32-grade.
// SAMPLE: no C store; per-row argmax(logit+gumbel) merged into row_best.
template<int NSEG, bool BIAS, bool QGELU, bool RES, bool SAMPLE>
__global__ __launch_bounds__(256) void k_gemm(
    const float* __restrict__ A, const float* __restrict__ B, float* __restrict__ C,
    const float* __restrict__ bias, const float* __restrict__ res,
    int M, int N, int K, uint32_t kf0, uint32_t kf1,
    unsigned long long* __restrict__ row_best)
{
  __shared__ unsigned short sA[128*64];   // [m][k] bf16, 16B-chunk XOR swizzled
  __shared__ unsigned short sB[128*64];   // [n][k] bf16 (transposed), same swizzle
  const int t = threadIdx.x;
  const int bn = blockIdx.x, bm = blockIdx.y;
  const int wave = t >> 6, lane = t & 63;
  const int wm = wave >> 1, wn = wave & 1;
  const int g = lane >> 4, r = lane & 15;

  f32x4 acc[4][4] = {};

  const int nK = K >> 6;
  const int aC = t & 7,  aM0 = t >> 3;
  const int bN0 = t & 31, bC = t >> 5;
  const float* Abase = A + (size_t)(bm*128) * K;
  const float* Bbase = B + (size_t)(bn*128);

  for (int seg = 0; seg < NSEG; ++seg) {
    const bool aLO = (seg == 1), bLO = (seg == 2);
    for (int kb = 0; kb < nK; ++kb) {
      const int k0 = kb << 6;
      __syncthreads();
      // stage A tile 128x64
      #pragma unroll
      for (int p=0;p<4;p++){
        int m = p*32 + aM0;
        const float* src = Abase + (size_t)m * K + k0 + aC*8;
        float ff[8];
        *(float4*)(ff)   = *(const float4*)(src);
        *(float4*)(ff+4) = *(const float4*)(src+4);
        unsigned short hh[8];
        cvt8(ff, aLO, hh);
        *(bf16x8*)&sA[m*64 + ((aC ^ (m & 7)) * 8)] = *(bf16x8*)hh;
      }
      // stage B tile 64x128 (transpose into [n][k])
      #pragma unroll
      for (int p=0;p<4;p++){
        int n = p*32 + bN0;
        float ff[8];
        const float* src = Bbase + (size_t)(k0 + bC*8) * N + n;
        #pragma unroll
        for (int e=0;e<8;e++) ff[e] = src[(size_t)e * N];
        unsigned short hh[8];
        cvt8(ff, bLO, hh);
        *(bf16x8*)&sB[n*64 + ((bC ^ (n & 7)) * 8)] = *(bf16x8*)hh;
      }
      __syncthreads();
      #pragma unroll
      for (int kk=0;kk<2;kk++){
        bf16x8 av[4], bv[4];
        #pragma unroll
        for (int mi=0;mi<4;mi++){
          int m = wm*64 + mi*16 + r;
          av[mi] = *(const bf16x8*)&sA[m*64 + (((kk*4 + g) ^ (m & 7)) * 8)];
        }
        #pragma unroll
        for (int ni=0;ni<4;ni++){
          int n = wn*64 + ni*16 + r;
          bv[ni] = *(const bf16x8*)&sB[n*64 + (((kk*4 + g) ^ (n & 7)) * 8)];
        }
        #pragma unroll
        for (int mi=0;mi<4;mi++)
          #pragma unroll
          for (int ni=0;ni<4;ni++)
            acc[mi][ni] = __builtin_amdgcn_mfma_f32_16x16x32_bf16(av[mi], bv[ni], acc[mi][ni], 0, 0, 0);
      }
    }
  }

  if constexpr (SAMPLE) {
    #pragma unroll
    for (int mi=0;mi<4;mi++){
      #pragma unroll
      for (int jj=0;jj<4;jj++){
        uint32_t tm = bm*128 + wm*64 + mi*16 + g*4 + jj;
        unsigned long long best = 0ull;
        #pragma unroll
        for (int ni=0;ni<4;ni++){
          uint32_t v = bn*128 + wn*64 + ni*16 + r;
          float val = acc[mi][ni][jj] + gumbel_tv(kf0, kf1, tm, v);
          uint32_t fb = __float_as_uint(val);
          fb = (fb & 0x80000000u) ? ~fb : (fb | 0x80000000u);  // order-preserving
          unsigned long long packed = ((unsigned long long)fb << 32) | (unsigned long long)(~v);
          if (packed > best) best = packed;   // ties -> smaller v (first-index argmax)
        }
        #pragma unroll
        for (int off=1; off<16; off<<=1){
          unsigned int blo = (unsigned int)best, bhi = (unsigned int)(best >> 32);
          unsigned int olo = __shfl_xor(blo, off);
          unsigned int ohi = __shfl_xor(bhi, off);
          unsigned long long o = ((unsigned long long)ohi << 32) | (unsigned long long)olo;
          if (o > best) best = o;
        }
        if (r == 0) atomicMax(&row_best[tm], best);
      }
    }
  } else {
    #pragma unroll
    for (int mi=0;mi<4;mi++)
      #pragma unroll
      for (int ni=0;ni<4;ni++)
        #pragma unroll
        for (int jj=0;jj<4;jj++){
          int m = bm*128 + wm*64 + mi*16 + g*4 + jj;
          int n = bn*128 + wn*64 + ni*16 + r;
          float v = acc[mi][ni][jj];
          if constexpr (BIAS)  v += bias[n];
          if constexpr (QGELU) v = v / (1.0f + expf(-1.702f * v));
          if constexpr (RES)   v += res[(size_t)m * N + n];
          C[(size_t)m * N + n] = v;
        }
  }
}

// ---------------- embed + LN (fused), and plain LN over D=768 ----------------
__global__ __launch_bounds__(256) void k_embed_ln(const int* __restrict__ idx,
    const float* __restrict__ wte, const float* __restrict__ g, const float* __restrict__ b,
    float* __restrict__ Xraw, float* __restrict__ H)
{
  int row = blockIdx.x;
  const float* src = wte + (size_t)idx[row] * DIM;
  float v[3];
  #pragma unroll
  for (int jj=0;jj<3;jj++) v[jj] = src[threadIdx.x + jj*256];
  float s = blockReduceSum(v[0]+v[1]+v[2]);
  float mean = s * (1.0f/DIM);
  float s2 = 0;
  #pragma unroll
  for (int jj=0;jj<3;jj++){ float d = v[jj]-mean; s2 += d*d; }
  s2 = blockReduceSum(s2);
  float rs = rsqrtf(s2 * (1.0f/DIM) + 1e-5f);
  #pragma unroll
  for (int jj=0;jj<3;jj++){
    int d = threadIdx.x + jj*256;
    Xraw[(size_t)row*DIM + d] = v[jj];
    H[(size_t)row*DIM + d] = (v[jj]-mean)*rs*g[d] + b[d];
  }
}

__global__ __launch_bounds__(256) void k_ln(const float* __restrict__ in, float* __restrict__ out,
    const float* __restrict__ g, const float* __restrict__ b)
{
  int row = blockIdx.x;
  const float* src = in + (size_t)row * DIM;
  float v[3];
  #pragma unroll
  for (int jj=0;jj<3;jj++) v[jj] = src[threadIdx.x + jj*256];
  float s = blockReduceSum(v[0]+v[1]+v[2]);
  float mean = s * (1.0f/DIM);
  float s2 = 0;
  #pragma unroll
  for (int jj=0;jj<3;jj++){ float d = v[jj]-mean; s2 += d*d; }
  s2 = blockReduceSum(s2);
  float rs = rsqrtf(s2 * (1.0f/DIM) + 1e-5f);
  #pragma unroll
  for (int jj=0;jj<3;jj++){
    int d = threadIdx.x + jj*256;
    out[(size_t)row*DIM + d] = (v[jj]-mean)*rs*g[d] + b[d];
  }
}

// ---------------- mask compaction ----------------
__global__ void k_mask(const unsigned long long* __restrict__ row_best,
    const int* __restrict__ idx, int j, int* __restrict__ count, int* __restrict__ plist)
{
  int t = blockIdx.x * blockDim.x + threadIdx.x;
  if (t >= T_TOK) return;
  int v = (int)(~(uint32_t)(row_best[t] & 0xFFFFFFFFull));
  int tgt = (t < T_TOK-1) ? idx[t+1] : -1;
  if (v == tgt && t < T_TOK - j){
    int pos = atomicAdd(count, 1);
    plist[pos] = t;
  }
}

// ---------------- sparse merge MLP (only masked rows) ----------------
__global__ __launch_bounds__(256) void k_merge(const float* __restrict__ X,
    const int* __restrict__ plist, const int* __restrict__ count,
    const float* __restrict__ lng, const float* __restrict__ lnb,
    const float* __restrict__ fcw, const float* __restrict__ fcb,
    const float* __restrict__ pjw, const float* __restrict__ pjb,
    float* __restrict__ mergebuf, int j)
{
  __shared__ float sh[1536 + 3072];
  int nb = *count;
  for (int bIdx = blockIdx.x; bIdx < nb; bIdx += gridDim.x){
    int p = plist[bIdx];
    const float* xp = X + (size_t)p * DIM;
    const float* x2 = X + (size_t)(p + j) * DIM;
    for (int d = threadIdx.x; d < 1536; d += 256)
      sh[d] = (d < DIM) ? xp[d] : x2[d - DIM];
    __syncthreads();
    float s = 0;
    for (int d = threadIdx.x; d < 1536; d += 256) s += sh[d];
    s = blockReduceSum(s);
    float mean = s * (1.0f/1536.0f);
    float s2 = 0;
    for (int d = threadIdx.x; d < 1536; d += 256){ float df = sh[d]-mean; s2 += df*df; }
    s2 = blockReduceSum(s2);
    float rs = rsqrtf(s2 * (1.0f/1536.0f) + 1e-5f);
    __syncthreads();
    for (int d = threadIdx.x; d < 1536; d += 256)
      sh[d] = (sh[d]-mean)*rs*lng[d] + lnb[d];
    __syncthreads();
    float* act = sh + 1536;
    #pragma unroll
    for (int jj=0;jj<12;jj++){
      int n = threadIdx.x + jj*256;
      float a = fcb[n];
      for (int k=0;k<1536;k++) a += sh[k]*fcw[(size_t)k*3072 + n];
      act[n] = a / (1.0f + expf(-1.702f*a));
    }
    __syncthreads();
    #pragma unroll
    for (int jj=0;jj<3;jj++){
      int d = threadIdx.x + jj*256;
      float a = pjb[d];
      for (int k=0;k<3072;k++) a += act[k]*pjw[(size_t)k*DIM + d];
      mergebuf[(size_t)bIdx*DIM + d] = x2[d] + a;
    }
    __syncthreads();
  }
}

__global__ void k_scatter(float* __restrict__ X, const float* __restrict__ mergebuf,
    const int* __restrict__ plist, const int* __restrict__ count, int j)
{
  int nb = *count;
  for (int bIdx = blockIdx.x; bIdx < nb; bIdx += gridDim.x){
    int p = plist[bIdx];
    for (int d = threadIdx.x; d < DIM; d += 256)
      X[(size_t)(p + j)*DIM + d] = mergebuf[(size_t)bIdx*DIM + d];
  }
}

// ---------------- host ----------------
static void fold_key(uint32_t i, uint32_t& o0, uint32_t& o1){
  // jax.random.fold_in(key(42), i) = threefry2x32(key=[0,42], count=[0,i])
  uint32_t x0 = 0, x1 = i;
  tf2x32(0u, 42u, x0, x1);
  o0 = x0; o1 = x1;
}

extern "C" void kernel_launch(void* const* d_in, const int* in_sizes, int n_in,
                              void* d_out, int out_size, void* d_ws, size_t ws_size,
                              hipStream_t stream)
{
  const int*   idx       = (const int*)  d_in[0];
  const float* wte       = (const float*)d_in[1];
  const float* rb_ln_g   = (const float*)d_in[2];
  const float* rb_ln_b   = (const float*)d_in[3];
  const float* rb_fc_w   = (const float*)d_in[4];
  const float* rb_fc_b   = (const float*)d_in[5];
  const float* rb_proj_w = (const float*)d_in[6];
  const float* rb_proj_b = (const float*)d_in[7];
  const float* lnf_g     = (const float*)d_in[8];
  const float* lnf_b     = (const float*)d_in[9];
  const float* lm_head_w = (const float*)d_in[10];
  const float* mb_ln_g   = (const float*)d_in[11];
  const float* mb_ln_b   = (const float*)d_in[12];
  const float* mb_fc_w   = (const float*)d_in[13];
  const float* mb_fc_b   = (const float*)d_in[14];
  const float* mb_proj_w = (const float*)d_in[15];
  const float* mb_proj_b = (const float*)d_in[16];
  const float* op_w      = (const float*)d_in[17];
  const float* op_b      = (const float*)d_in[18];
  const float* lns_g     = (const float*)d_in[19];
  const float* lns_b     = (const float*)d_in[20];
  const float* heads_w   = (const float*)d_in[21];

  // ws: X, H, Y  (3 x T*D f32 = 37.7 MB)
  float* X = (float*)d_ws;
  float* H = X + (size_t)T_TOK*DIM;
  float* Y = H + (size_t)T_TOK*DIM;

  // scratch inside d_out (all consumed before the final head GEMM writes d_out)
  float* OUT   = (float*)d_out;
  float* ACT   = OUT;                                   // T*3072
  float* MERGE = OUT + (size_t)T_TOK*3072;              // T*768
  unsigned long long* ROWBEST = (unsigned long long*)(MERGE + (size_t)T_TOK*DIM); // T u64
  int* PLIST = (int*)(ROWBEST + T_TOK);                 // T i32
  int* COUNT = PLIST + T_TOK;                           // 1 i32

  dim3 blk(256);

  // 1) embed + rb_ln
  k_embed_ln<<<T_TOK, blk, 0, stream>>>(idx, wte, rb_ln_g, rb_ln_b, X, H);
  // 2) fc (split-bf16) + bias + qgelu -> ACT
  k_gemm<3,true,true,false,false><<<dim3(3072/128, T_TOK/128), blk, 0, stream>>>(
      H, rb_fc_w, ACT, rb_fc_b, nullptr, T_TOK, 3072, DIM, 0u, 0u, nullptr);
  // 3) proj (split) + bias + residual(X) -> Y
  k_gemm<3,true,false,true,false><<<dim3(DIM/128, T_TOK/128), blk, 0, stream>>>(
      ACT, rb_proj_w, Y, rb_proj_b, X, T_TOK, DIM, 3072, 0u, 0u, nullptr);
  // 4) lnf -> X
  k_ln<<<T_TOK, blk, 0, stream>>>(Y, X, lnf_g, lnf_b);

  for (int i = 0; i < NLAYER; ++i){
    int j = i + 1;
    uint32_t kf0, kf1; fold_key((uint32_t)i, kf0, kf1);

    hipMemsetAsync(ROWBEST, 0, (size_t)T_TOK*8, stream);
    hipMemsetAsync(COUNT, 0, 4, stream);

    const float* hw = (i == 0) ? lm_head_w : heads_w + (size_t)(i-1)*DIM*VOCAB;
    // sampling head: bf16 MFMA + fused gumbel-argmax (no logits store)
    k_gemm<1,false,false,false,true><<<dim3(VOCAB/128, T_TOK/128), blk, 0, stream>>>(
        X, hw, nullptr, nullptr, nullptr, T_TOK, VOCAB, DIM, kf0, kf1, ROWBEST);

    k_mask<<<T_TOK/256, blk, 0, stream>>>(ROWBEST, idx, j, COUNT, PLIST);
    k_merge<<<64, blk, 0, stream>>>(X, PLIST, COUNT,
        mb_ln_g + (size_t)i*1536, mb_ln_b + (size_t)i*1536,
        mb_fc_w + (size_t)i*1536*3072, mb_fc_b + (size_t)i*3072,
        mb_proj_w + (size_t)i*3072*DIM, mb_proj_b + (size_t)i*DIM, MERGE, j);
    k_scatter<<<64, blk, 0, stream>>>(X, MERGE, PLIST, COUNT, j);

    // op (split) + bias -> Y ; then lns -> X
    k_gemm<3,true,false,false,false><<<dim3(DIM/128, T_TOK/128), blk, 0, stream>>>(
        X, op_w + (size_t)i*DIM*DIM, Y, op_b + (size_t)i*DIM, nullptr,
        T_TOK, DIM, DIM, 0u, 0u, nullptr);
    k_ln<<<T_TOK, blk, 0, stream>>>(Y, X, lns_g + (size_t)i*DIM, lns_b + (size_t)i*DIM);
  }

  // final head (split-bf16, f32-grade) -> d_out
  k_gemm<3,false,false,false,false><<<dim3(VOCAB/128, T_TOK/128), blk, 0, stream>>>(
      X, heads_w + (size_t)3*DIM*VOCAB, OUT, nullptr, nullptr,
      T_TOK, VOCAB, DIM, 0u, 0u, nullptr);
}

// Round 2
// 3071.691 us; speedup vs baseline: 2.1437x; 2.1437x over previous
//
#include <hip/hip_runtime.h>
#include <cstdint>
#include <cstddef>

#define T_TOK 4096
#define DIM   768
#define VOCAB 32000
#define NLAYER 4
#define HALF_TV 65536000u   // T*V/2

typedef short bf16x8 __attribute__((ext_vector_type(8)));
typedef float f32x4  __attribute__((ext_vector_type(4)));

// ---------------- threefry2x32 (exact JAX semantics) ----------------
__host__ __device__ inline void tf2x32(uint32_t k0, uint32_t k1, uint32_t& v0, uint32_t& v1){
  uint32_t ks2 = k0 ^ k1 ^ 0x1BD11BDAu;
  uint32_t x0 = v0 + k0, x1 = v1 + k1;
#define TFR(R) { x0 += x1; x1 = (x1<<R)|(x1>>(32-R)); x1 ^= x0; }
  TFR(13) TFR(15) TFR(26) TFR(6)
  x0 += k1;  x1 += ks2 + 1u;
  TFR(17) TFR(29) TFR(16) TFR(24)
  x0 += ks2; x1 += k0 + 2u;
  TFR(13) TFR(15) TFR(26) TFR(6)
  x0 += k0;  x1 += k1 + 3u;
  TFR(17) TFR(29) TFR(16) TFR(24)
  x0 += k1;  x1 += ks2 + 4u;
  TFR(13) TFR(15) TFR(26) TFR(6)
  x0 += ks2; x1 += k0 + 5u;
#undef TFR
  v0 = x0; v1 = x1;
}

// One threefry call -> gumbel for (t_up, v) AND (t_up+2048, v).  t_up < 2048 so
// m = t_up*V+v < HALF_TV always; counter pair (m, m+HALF) matches JAX's split.
__device__ inline void gumbel_pair(uint32_t kf0, uint32_t kf1, uint32_t t_up, uint32_t v,
                                   float& gu, float& gd){
  uint32_t m = t_up * (uint32_t)VOCAB + v;
  uint32_t x0 = m, x1 = m + HALF_TV;
  tf2x32(kf0, kf1, x0, x1);
  uint32_t ku = x0 >> 9, kd = x1 >> 9;
  float uu = ku ? (float)ku * 1.1920928955078125e-7f : 1.17549435082228751e-38f;
  float ud = kd ? (float)kd * 1.1920928955078125e-7f : 1.17549435082228751e-38f;
  gu = -logf(-logf(uu));
  gd = -logf(-logf(ud));
}

// ---------------- helpers ----------------
__device__ inline unsigned short f2bf(float f){  // RNE f32->bf16
  uint32_t u = __float_as_uint(f);
  return (unsigned short)((u + 0x7FFFu + ((u >> 16) & 1u)) >> 16);
}
__device__ inline float bf2f(unsigned short h){
  return __uint_as_float(((uint32_t)h) << 16);
}
__device__ inline void cvt8(const float* f, bool lo, unsigned short* out){
  #pragma unroll
  for (int e=0;e<8;e++){
    float x = f[e];
    unsigned short h = f2bf(x);
    if (lo) h = f2bf(x - bf2f(h));
    out[e] = h;
  }
}
__device__ inline float blockReduceSum(float v){
  __shared__ float red[4];
  #pragma unroll
  for (int off=32; off>0; off>>=1) v += __shfl_down(v, off);
  int w = threadIdx.x >> 6;
  __syncthreads();
  if ((threadIdx.x & 63) == 0) red[w] = v;
  __syncthreads();
  return red[0] + red[1] + red[2] + red[3];
}

// async global->LDS, 16B per lane (dest must be linear: wave base + lane*16)
__device__ inline void gload16(const void* g, void* l){
  __builtin_amdgcn_global_load_lds(
      (const __attribute__((address_space(1))) unsigned int*)g,
      (__attribute__((address_space(3))) unsigned int*)l, 16, 0, 0);
}

// =====================================================================
// k_hgemm: C[M=4096, N] = A[4096,K] @ Bt[N,K]^T, bf16 inputs, f32 acc.
// Virtual segments for split-bf16: seg0 = Ahi*Bhi, seg1 = Alo*Bhi, seg2 = Ahi*Blo.
// M-tile rows interleave slabs {t, t+2048} at 16-row granularity so the SAMPLE
// epilogue can share one threefry call across the row pair.
// =====================================================================
enum { ST_F32 = 0, ST_HILO = 1, ST_SAMPLE = 2 };

template<int KSTEPS, int NSEG, bool BIAS, bool QGELU, bool RES, int STORE>
__global__ __launch_bounds__(256) void k_hgemm(
    const unsigned short* __restrict__ A0, const unsigned short* __restrict__ A1,
    const unsigned short* __restrict__ B0, const unsigned short* __restrict__ B2,
    float* __restrict__ C, unsigned short* __restrict__ Ch, unsigned short* __restrict__ Cl,
    const float* __restrict__ bias, const float* __restrict__ res,
    int N, uint32_t kf0, uint32_t kf1, unsigned long long* __restrict__ row_best)
{
  constexpr int K = KSTEPS * 64;
  __shared__ unsigned short sA[128*64];
  __shared__ unsigned short sB[128*64];
  const int t = threadIdx.x;
  const int wave = t >> 6, lane = t & 63;
  const int wm = wave >> 1, wn = wave & 1;
  const int g = lane >> 4, r = lane & 15;
  const int lr = lane >> 3, lc = lane & 7;

  // XCD-chunked swizzle: xcd gets bm-pairs [xcd*4, xcd*4+4), bn streams.
  int bid = blockIdx.x;
  int xcd = bid & 7, c = bid >> 3;
  int bm = xcd*4 + (c & 3);
  int bn = c >> 2;

  f32x4 acc[4][4] = {};

  for (int kb = 0; kb < NSEG*KSTEPS; ++kb){
    const int seg = (NSEG == 1) ? 0 : (kb / KSTEPS);
    const int k0  = (NSEG == 1) ? kb*64 : (kb % KSTEPS) * 64;
    const unsigned short* Ap = (seg == 1) ? A1 : A0;
    const unsigned short* Bp = (seg == 2) ? B2 : B0;
    __syncthreads();
    #pragma unroll
    for (int p=0;p<4;p++){
      int mr = p*32 + wave*8 + lr;            // tile-local row; mr&7 == lr
      int blk = mr >> 4;
      int grow = bm*64 + ((blk>>1)<<4) + (mr & 15) + ((blk & 1) ? 2048 : 0);
      int gk = k0 + ((lc ^ lr) << 3);         // pre-swizzled global source chunk
      gload16(Ap + (size_t)grow * K + gk, (char*)sA + mr*128 + lc*16);
      int nrow = bn*128 + mr;
      gload16(Bp + (size_t)nrow * K + gk, (char*)sB + mr*128 + lc*16);
    }
    __syncthreads();
    #pragma unroll
    for (int kk=0;kk<2;kk++){
      bf16x8 av[4], bv[4];
      #pragma unroll
      for (int mi=0;mi<4;mi++){
        int tr = wm*64 + mi*16 + r;
        av[mi] = *(const bf16x8*)((const char*)sA + tr*128 + (((kk*4+g) ^ (r&7))<<4));
      }
      #pragma unroll
      for (int ni=0;ni<4;ni++){
        int tr = wn*64 + ni*16 + r;
        bv[ni] = *(const bf16x8*)((const char*)sB + tr*128 + (((kk*4+g) ^ (r&7))<<4));
      }
      #pragma unroll
      for (int mi=0;mi<4;mi++)
        #pragma unroll
        for (int ni=0;ni<4;ni++)
          acc[mi][ni] = __builtin_amdgcn_mfma_f32_16x16x32_bf16(av[mi], bv[ni], acc[mi][ni], 0, 0, 0);
    }
  }

  if constexpr (STORE == ST_SAMPLE){
    #pragma unroll
    for (int mi=0; mi<4; mi+=2){
      int row16 = ((wm*4 + mi) >> 1) << 4;
      #pragma unroll
      for (int jj=0;jj<4;jj++){
        uint32_t t_up = bm*64 + row16 + g*4 + jj;   // < 2048
        unsigned long long bu = 0ull, bd = 0ull;
        #pragma unroll
        for (int ni=0;ni<4;ni++){
          uint32_t v = bn*128 + wn*64 + ni*16 + r;
          float gu, gd;
          gumbel_pair(kf0, kf1, t_up, v, gu, gd);
          float vu = acc[mi][ni][jj]   + gu;
          float vd = acc[mi+1][ni][jj] + gd;
          uint32_t fu = __float_as_uint(vu); fu = (fu & 0x80000000u) ? ~fu : (fu | 0x80000000u);
          uint32_t fd = __float_as_uint(vd); fd = (fd & 0x80000000u) ? ~fd : (fd | 0x80000000u);
          unsigned long long pu = ((unsigned long long)fu << 32) | (unsigned long long)(~v);
          unsigned long long pd = ((unsigned long long)fd << 32) | (unsigned long long)(~v);
          if (pu > bu) bu = pu;
          if (pd > bd) bd = pd;
        }
        #pragma unroll
        for (int off=1; off<16; off<<=1){
          unsigned int l0 = (unsigned int)bu, h0 = (unsigned int)(bu>>32);
          unsigned int l1 = __shfl_xor(l0, off), h1 = __shfl_xor(h0, off);
          unsigned long long o = ((unsigned long long)h1 << 32) | (unsigned long long)l1;
          if (o > bu) bu = o;
          l0 = (unsigned int)bd; h0 = (unsigned int)(bd>>32);
          l1 = __shfl_xor(l0, off); h1 = __shfl_xor(h0, off);
          o = ((unsigned long long)h1 << 32) | (unsigned long long)l1;
          if (o > bd) bd = o;
        }
        if (r == 0){
          atomicMax(&row_best[t_up], bu);
          atomicMax(&row_best[t_up + 2048], bd);
        }
      }
    }
  } else {
    #pragma unroll
    for (int mi=0;mi<4;mi++){
      int blk2 = wm*4 + mi;
      int mbase = bm*64 + ((blk2>>1)<<4) + ((blk2 & 1) ? 2048 : 0);
      #pragma unroll
      for (int ni=0;ni<4;ni++){
        int n = bn*128 + wn*64 + ni*16 + r;
        float bv_ = BIAS ? bias[n] : 0.0f;
        #pragma unroll
        for (int jj=0;jj<4;jj++){
          int m = mbase + g*4 + jj;
          float v = acc[mi][ni][jj] + bv_;
          if constexpr (QGELU) v = v / (1.0f + expf(-1.702f * v));
          if constexpr (RES)   v += res[(size_t)m * N + n];
          if constexpr (STORE == ST_F32){
            C[(size_t)m * N + n] = v;
          } else {
            unsigned short h = f2bf(v);
            Ch[(size_t)m * N + n] = h;
            Cl[(size_t)m * N + n] = f2bf(v - bf2f(h));
          }
        }
      }
    }
  }
}

// ---------------- weight transpose + f32->bf16 (hi[/lo]) ----------------
// W[K][N] f32  ->  Bt[N][K] bf16 (hi and optionally lo)
template<bool SPLIT>
__global__ __launch_bounds__(256) void k_wt_t(const float* __restrict__ W,
    unsigned short* __restrict__ Bh, unsigned short* __restrict__ Bl, int K, int N)
{
  __shared__ unsigned short sH[64][72];
  __shared__ unsigned short sL[64][72];
  int kt = blockIdx.x, nt = blockIdx.y;
  int t = threadIdx.x;
  int kr = t >> 4, nc4 = (t & 15) * 4;
  #pragma unroll
  for (int p=0;p<4;p++){
    int k = p*16 + kr;
    float4 w = *(const float4*)&W[(size_t)(kt*64 + k) * N + nt*64 + nc4];
    const float* wf = (const float*)&w;
    #pragma unroll
    for (int e=0;e<4;e++){
      unsigned short h = f2bf(wf[e]);
      sH[nc4+e][k] = h;
      if (SPLIT) sL[nc4+e][k] = f2bf(wf[e] - bf2f(h));
    }
  }
  __syncthreads();
  #pragma unroll
  for (int q=0;q<2;q++){
    int cid = t + q*256;
    int n = cid >> 3, ch = cid & 7;
    *(bf16x8*)&Bh[(size_t)(nt*64+n)*K + kt*64 + ch*8] = *(const bf16x8*)&sH[n][ch*8];
    if (SPLIT)
      *(bf16x8*)&Bl[(size_t)(nt*64+n)*K + kt*64 + ch*8] = *(const bf16x8*)&sL[n][ch*8];
  }
}

// ---------------- embed + LN (emits bf16 hi/lo of LN output) ----------------
__global__ __launch_bounds__(256) void k_embed_ln(const int* __restrict__ idx,
    const float* __restrict__ wte, const float* __restrict__ g, const float* __restrict__ b,
    float* __restrict__ Xraw, unsigned short* __restrict__ Hh, unsigned short* __restrict__ Hl)
{
  int row = blockIdx.x;
  const float* src = wte + (size_t)idx[row] * DIM;
  float v[3];
  #pragma unroll
  for (int jj=0;jj<3;jj++) v[jj] = src[threadIdx.x + jj*256];
  float s = blockReduceSum(v[0]+v[1]+v[2]);
  float mean = s * (1.0f/DIM);
  float s2 = 0;
  #pragma unroll
  for (int jj=0;jj<3;jj++){ float d = v[jj]-mean; s2 += d*d; }
  s2 = blockReduceSum(s2);
  float rs = rsqrtf(s2 * (1.0f/DIM) + 1e-5f);
  #pragma unroll
  for (int jj=0;jj<3;jj++){
    int d = threadIdx.x + jj*256;
    Xraw[(size_t)row*DIM + d] = v[jj];
    float o = (v[jj]-mean)*rs*g[d] + b[d];
    unsigned short h = f2bf(o);
    Hh[(size_t)row*DIM + d] = h;
    Hl[(size_t)row*DIM + d] = f2bf(o - bf2f(h));
  }
}

// LN: Y -> X (f32) + Xbf (hi) + Xlo
__global__ __launch_bounds__(256) void k_ln(const float* __restrict__ in, float* __restrict__ out,
    const float* __restrict__ g, const float* __restrict__ b,
    unsigned short* __restrict__ obf, unsigned short* __restrict__ olo)
{
  int row = blockIdx.x;
  const float* src = in + (size_t)row * DIM;
  float v[3];
  #pragma unroll
  for (int jj=0;jj<3;jj++) v[jj] = src[threadIdx.x + jj*256];
  float s = blockReduceSum(v[0]+v[1]+v[2]);
  float mean = s * (1.0f/DIM);
  float s2 = 0;
  #pragma unroll
  for (int jj=0;jj<3;jj++){ float d = v[jj]-mean; s2 += d*d; }
  s2 = blockReduceSum(s2);
  float rs = rsqrtf(s2 * (1.0f/DIM) + 1e-5f);
  #pragma unroll
  for (int jj=0;jj<3;jj++){
    int d = threadIdx.x + jj*256;
    float o = (v[jj]-mean)*rs*g[d] + b[d];
    out[(size_t)row*DIM + d] = o;
    unsigned short h = f2bf(o);
    obf[(size_t)row*DIM + d] = h;
    olo[(size_t)row*DIM + d] = f2bf(o - bf2f(h));
  }
}

// ---------------- mask compaction ----------------
__global__ void k_mask(const unsigned long long* __restrict__ row_best,
    const int* __restrict__ idx, int j, int* __restrict__ count, int* __restrict__ plist)
{
  int t = blockIdx.x * blockDim.x + threadIdx.x;
  if (t >= T_TOK) return;
  int v = (int)(~(uint32_t)(row_best[t] & 0xFFFFFFFFull));
  int tgt = (t < T_TOK-1) ? idx[t+1] : -1;
  if (v == tgt && t < T_TOK - j){
    int pos = atomicAdd(count, 1);
    plist[pos] = t;
  }
}

// ---------------- sparse merge MLP (only masked rows) ----------------
__global__ __launch_bounds__(256) void k_merge(const float* __restrict__ X,
    const int* __restrict__ plist, const int* __restrict__ count,
    const float* __restrict__ lng, const float* __restrict__ lnb,
    const float* __restrict__ fcw, const float* __restrict__ fcb,
    const float* __restrict__ pjw, const float* __restrict__ pjb,
    float* __restrict__ mergebuf, int j)
{
  __shared__ float sh[1536 + 3072];
  int nb = *count;
  for (int bIdx = blockIdx.x; bIdx < nb; bIdx += gridDim.x){
    int p = plist[bIdx];
    const float* xp = X + (size_t)p * DIM;
    const float* x2 = X + (size_t)(p + j) * DIM;
    for (int d = threadIdx.x; d < 1536; d += 256)
      sh[d] = (d < DIM) ? xp[d] : x2[d - DIM];
    __syncthreads();
    float s = 0;
    for (int d = threadIdx.x; d < 1536; d += 256) s += sh[d];
    s = blockReduceSum(s);
    float mean = s * (1.0f/1536.0f);
    float s2 = 0;
    for (int d = threadIdx.x; d < 1536; d += 256){ float df = sh[d]-mean; s2 += df*df; }
    s2 = blockReduceSum(s2);
    float rs = rsqrtf(s2 * (1.0f/1536.0f) + 1e-5f);
    __syncthreads();
    for (int d = threadIdx.x; d < 1536; d += 256)
      sh[d] = (sh[d]-mean)*rs*lng[d] + lnb[d];
    __syncthreads();
    float* act = sh + 1536;
    #pragma unroll
    for (int jj=0;jj<12;jj++){
      int n = threadIdx.x + jj*256;
      float a = fcb[n];
      for (int k=0;k<1536;k++) a += sh[k]*fcw[(size_t)k*3072 + n];
      act[n] = a / (1.0f + expf(-1.702f*a));
    }
    __syncthreads();
    #pragma unroll
    for (int jj=0;jj<3;jj++){
      int d = threadIdx.x + jj*256;
      float a = pjb[d];
      for (int k=0;k<3072;k++) a += act[k]*pjw[(size_t)k*DIM + d];
      mergebuf[(size_t)bIdx*DIM + d] = x2[d] + a;
    }
    __syncthreads();
  }
}

__global__ void k_scatter(float* __restrict__ X, unsigned short* __restrict__ Xbf,
    unsigned short* __restrict__ Xlo, const float* __restrict__ mergebuf,
    const int* __restrict__ plist, const int* __restrict__ count, int j)
{
  int nb = *count;
  for (int bIdx = blockIdx.x; bIdx < nb; bIdx += gridDim.x){
    int p = plist[bIdx];
    for (int d = threadIdx.x; d < DIM; d += 256){
      float v = mergebuf[(size_t)bIdx*DIM + d];
      size_t o = (size_t)(p + j)*DIM + d;
      X[o] = v;
      unsigned short h = f2bf(v);
      Xbf[o] = h;
      Xlo[o] = f2bf(v - bf2f(h));
    }
  }
}

// ---------------- fallback final-head GEMM (f32 in, split-bf16, old path) ----
__global__ __launch_bounds__(256) void k_gemm_old(
    const float* __restrict__ A, const float* __restrict__ B, float* __restrict__ C,
    int M, int N, int K)
{
  __shared__ unsigned short sA[128*64];
  __shared__ unsigned short sB[128*64];
  const int t = threadIdx.x;
  const int bn = blockIdx.x, bm = blockIdx.y;
  const int wave = t >> 6, lane = t & 63;
  const int wm = wave >> 1, wn = wave & 1;
  const int g = lane >> 4, r = lane & 15;
  f32x4 acc[4][4] = {};
  const int nK = K >> 6;
  const int aC = t & 7,  aM0 = t >> 3;
  const int bN0 = t & 31, bC = t >> 5;
  const float* Abase = A + (size_t)(bm*128) * K;
  const float* Bbase = B + (size_t)(bn*128);
  for (int seg = 0; seg < 3; ++seg) {
    const bool aLO = (seg == 1), bLO = (seg == 2);
    for (int kb = 0; kb < nK; ++kb) {
      const int k0 = kb << 6;
      __syncthreads();
      #pragma unroll
      for (int p=0;p<4;p++){
        int m = p*32 + aM0;
        const float* src = Abase + (size_t)m * K + k0 + aC*8;
        float ff[8];
        *(float4*)(ff)   = *(const float4*)(src);
        *(float4*)(ff+4) = *(const float4*)(src+4);
        unsigned short hh[8];
        cvt8(ff, aLO, hh);
        *(bf16x8*)&sA[m*64 + ((aC ^ (m & 7)) * 8)] = *(bf16x8*)hh;
      }
      #pragma unroll
      for (int p=0;p<4;p++){
        int n = p*32 + bN0;
        float ff[8];
        const float* src = Bbase + (size_t)(k0 + bC*8) * N + n;
        #pragma unroll
        for (int e=0;e<8;e++) ff[e] = src[(size_t)e * N];
        unsigned short hh[8];
        cvt8(ff, bLO, hh);
        *(bf16x8*)&sB[n*64 + ((bC ^ (n & 7)) * 8)] = *(bf16x8*)hh;
      }
      __syncthreads();
      #pragma unroll
      for (int kk=0;kk<2;kk++){
        bf16x8 av[4], bv[4];
        #pragma unroll
        for (int mi=0;mi<4;mi++){
          int m = wm*64 + mi*16 + r;
          av[mi] = *(const bf16x8*)&sA[m*64 + (((kk*4 + g) ^ (m & 7)) * 8)];
        }
        #pragma unroll
        for (int ni=0;ni<4;ni++){
          int n = wn*64 + ni*16 + r;
          bv[ni] = *(const bf16x8*)&sB[n*64 + (((kk*4 + g) ^ (n & 7)) * 8)];
        }
        #pragma unroll
        for (int mi=0;mi<4;mi++)
          #pragma unroll
          for (int ni=0;ni<4;ni++)
            acc[mi][ni] = __builtin_amdgcn_mfma_f32_16x16x32_bf16(av[mi], bv[ni], acc[mi][ni], 0, 0, 0);
      }
    }
  }
  #pragma unroll
  for (int mi=0;mi<4;mi++)
    #pragma unroll
    for (int ni=0;ni<4;ni++)
      #pragma unroll
      for (int jj=0;jj<4;jj++){
        int m = bm*128 + wm*64 + mi*16 + g*4 + jj;
        int n = bn*128 + wn*64 + ni*16 + r;
        C[(size_t)m * N + n] = acc[mi][ni][jj];
      }
}

// ---------------- host ----------------
static void fold_key(uint32_t i, uint32_t& o0, uint32_t& o1){
  uint32_t x0 = 0, x1 = i;
  tf2x32(0u, 42u, x0, x1);
  o0 = x0; o1 = x1;
}

extern "C" void kernel_launch(void* const* d_in, const int* in_sizes, int n_in,
                              void* d_out, int out_size, void* d_ws, size_t ws_size,
                              hipStream_t stream)
{
  const int*   idx       = (const int*)  d_in[0];
  const float* wte       = (const float*)d_in[1];
  const float* rb_ln_g   = (const float*)d_in[2];
  const float* rb_ln_b   = (const float*)d_in[3];
  const float* rb_fc_w   = (const float*)d_in[4];
  const float* rb_fc_b   = (const float*)d_in[5];
  const float* rb_proj_w = (const float*)d_in[6];
  const float* rb_proj_b = (const float*)d_in[7];
  const float* lnf_g     = (const float*)d_in[8];
  const float* lnf_b     = (const float*)d_in[9];
  const float* lm_head_w = (const float*)d_in[10];
  const float* mb_ln_g   = (const float*)d_in[11];
  const float* mb_ln_b   = (const float*)d_in[12];
  const float* mb_fc_w   = (const float*)d_in[13];
  const float* mb_fc_b   = (const float*)d_in[14];
  const float* mb_proj_w = (const float*)d_in[15];
  const float* mb_proj_b = (const float*)d_in[16];
  const float* op_w      = (const float*)d_in[17];
  const float* op_b      = (const float*)d_in[18];
  const float* lns_g     = (const float*)d_in[19];
  const float* lns_b     = (const float*)d_in[20];
  const float* heads_w   = (const float*)d_in[21];

  const size_t TD = (size_t)T_TOK * DIM;
  const size_t DV = (size_t)DIM * VOCAB;

  // ---- d_ws: X, Y (f32) + Xbf, Xlo (bf16) [+ final-head Bt hi/lo if room]
  float* X = (float*)d_ws;
  float* Y = X + TD;
  unsigned short* Xbf = (unsigned short*)(Y + TD);
  unsigned short* Xlo = Xbf + TD;
  unsigned short* BtFh = Xlo + TD;
  unsigned short* BtFl = BtFh + DV;
  size_t need_big = (size_t)((char*)(BtFl + DV) - (char*)d_ws);
  bool big = ws_size >= need_big;

  // ---- d_out scratch (all consumed before final head GEMM overwrites d_out)
  char* ob = (char*)d_out;
  float* OUT = (float*)d_out;
  unsigned short* Hh     = (unsigned short*)(ob);                 // 2*TD bf16 = 12.6MB
  unsigned short* Hl     = Hh + TD;
  unsigned short* ACTh   = (unsigned short*)(ob + ((size_t)16<<20));  // 25.2MB
  unsigned short* ACTl   = ACTh + TD*4;
  unsigned short* Btfc_h = (unsigned short*)(ob + ((size_t)72<<20));  // [3072][768] x2
  unsigned short* Btfc_l = Btfc_h + (size_t)3072*DIM;
  unsigned short* Btpj_h = (unsigned short*)(ob + ((size_t)84<<20));  // [768][3072] x2
  unsigned short* Btpj_l = Btpj_h + (size_t)3072*DIM;
  unsigned short* BtS    = (unsigned short*)(ob + ((size_t)96<<20));  // [32000][768] 49.2MB
  unsigned short* Btop_h = (unsigned short*)(ob + ((size_t)152<<20)); // [768][768] x2
  unsigned short* Btop_l = Btop_h + (size_t)DIM*DIM;
  float* MERGE = (float*)(ob + ((size_t)160<<20));                    // 12.6MB
  unsigned long long* ROWBEST = (unsigned long long*)(ob + ((size_t)176<<20));
  int* PLIST = (int*)(ROWBEST + T_TOK);
  int* COUNT = PLIST + T_TOK;

  dim3 blk(256);

  // 1) embed + rb_ln -> X (f32), Hh/Hl (bf16 hi/lo)
  k_embed_ln<<<T_TOK, blk, 0, stream>>>(idx, wte, rb_ln_g, rb_ln_b, X, Hh, Hl);
  // 2) weight transposes for prologue MLP
  k_wt_t<true><<<dim3(12,48), blk, 0, stream>>>(rb_fc_w,   Btfc_h, Btfc_l, DIM,  3072);
  k_wt_t<true><<<dim3(48,12), blk, 0, stream>>>(rb_proj_w, Btpj_h, Btpj_l, 3072, DIM);
  // 3) fc (split) + bias + qgelu -> ACT hi/lo
  k_hgemm<12,3,true,true,false,ST_HILO><<<24*32, blk, 0, stream>>>(
      Hh, Hl, Btfc_h, Btfc_l, nullptr, ACTh, ACTl, rb_fc_b, nullptr, 3072, 0u,0u, nullptr);
  // 4) proj (split) + bias + residual(X) -> Y
  k_hgemm<48,3,true,false,true,ST_F32><<<6*32, blk, 0, stream>>>(
      ACTh, ACTl, Btpj_h, Btpj_l, Y, nullptr, nullptr, rb_proj_b, X, DIM, 0u,0u, nullptr);
  // 5) lnf -> X, Xbf, Xlo
  k_ln<<<T_TOK, blk, 0, stream>>>(Y, X, lnf_g, lnf_b, Xbf, Xlo);

  for (int i = 0; i < NLAYER; ++i){
    int j = i + 1;
    uint32_t kf0, kf1; fold_key((uint32_t)i, kf0, kf1);

    hipMemsetAsync(ROWBEST, 0, (size_t)T_TOK*8, stream);
    hipMemsetAsync(COUNT, 0, 4, stream);

    const float* hw = (i == 0) ? lm_head_w : heads_w + (size_t)(i-1)*DV;
    k_wt_t<false><<<dim3(12,500), blk, 0, stream>>>(hw, BtS, nullptr, DIM, VOCAB);
    // sampling head: bf16 MFMA + fused paired-threefry gumbel-argmax
    k_hgemm<12,1,false,false,false,ST_SAMPLE><<<250*32, blk, 0, stream>>>(
        Xbf, Xbf, BtS, BtS, nullptr, nullptr, nullptr, nullptr, nullptr,
        VOCAB, kf0, kf1, ROWBEST);

    k_mask<<<T_TOK/256, blk, 0, stream>>>(ROWBEST, idx, j, COUNT, PLIST);
    k_merge<<<64, blk, 0, stream>>>(X, PLIST, COUNT,
        mb_ln_g + (size_t)i*1536, mb_ln_b + (size_t)i*1536,
        mb_fc_w + (size_t)i*1536*3072, mb_fc_b + (size_t)i*3072,
        mb_proj_w + (size_t)i*3072*DIM, mb_proj_b + (size_t)i*DIM, MERGE, j);
    k_scatter<<<64, blk, 0, stream>>>(X, Xbf, Xlo, MERGE, PLIST, COUNT, j);

    // op (split) + bias -> Y ; then lns -> X, Xbf, Xlo
    k_wt_t<true><<<dim3(12,12), blk, 0, stream>>>(op_w + (size_t)i*DIM*DIM, Btop_h, Btop_l, DIM, DIM);
    k_hgemm<12,3,true,false,false,ST_F32><<<6*32, blk, 0, stream>>>(
        Xbf, Xlo, Btop_h, Btop_l, Y, nullptr, nullptr, op_b + (size_t)i*DIM, nullptr,
        DIM, 0u,0u, nullptr);
    k_ln<<<T_TOK, blk, 0, stream>>>(Y, X, lns_g + (size_t)i*DIM, lns_b + (size_t)i*DIM, Xbf, Xlo);
  }

  // final head (split-bf16, f32-grade) -> d_out
  if (big){
    k_wt_t<true><<<dim3(12,500), blk, 0, stream>>>(heads_w + (size_t)3*DV, BtFh, BtFl, DIM, VOCAB);
    k_hgemm<12,3,false,false,false,ST_F32><<<250*32, blk, 0, stream>>>(
        Xbf, Xlo, BtFh, BtFl, OUT, nullptr, nullptr, nullptr, nullptr, VOCAB, 0u,0u, nullptr);
  } else {
    k_gemm_old<<<dim3(VOCAB/128, T_TOK/128), blk, 0, stream>>>(
        X, heads_w + (size_t)3*DV, OUT, T_TOK, VOCAB, DIM);
  }
}

// Round 3
// 2816.830 us; speedup vs baseline: 2.3376x; 1.0905x over previous
//
#include <hip/hip_runtime.h>
#include <cstdint>
#include <cstddef>

#define T_TOK 4096
#define DIM   768
#define VOCAB 32000
#define NLAYER 4
#define HALF_TV 65536000u   // T*V/2

typedef short bf16x8 __attribute__((ext_vector_type(8)));
typedef float f32x4  __attribute__((ext_vector_type(4)));
typedef float f32x4v __attribute__((ext_vector_type(4)));

// ---------------- threefry2x32 (exact JAX semantics) ----------------
__host__ __device__ inline void tf2x32(uint32_t k0, uint32_t k1, uint32_t& v0, uint32_t& v1){
  uint32_t ks2 = k0 ^ k1 ^ 0x1BD11BDAu;
  uint32_t x0 = v0 + k0, x1 = v1 + k1;
#define TFR(R) { x0 += x1; x1 = (x1<<R)|(x1>>(32-R)); x1 ^= x0; }
  TFR(13) TFR(15) TFR(26) TFR(6)
  x0 += k1;  x1 += ks2 + 1u;
  TFR(17) TFR(29) TFR(16) TFR(24)
  x0 += ks2; x1 += k0 + 2u;
  TFR(13) TFR(15) TFR(26) TFR(6)
  x0 += k0;  x1 += k1 + 3u;
  TFR(17) TFR(29) TFR(16) TFR(24)
  x0 += k1;  x1 += ks2 + 4u;
  TFR(13) TFR(15) TFR(26) TFR(6)
  x0 += ks2; x1 += k0 + 5u;
#undef TFR
  v0 = x0; v1 = x1;
}

// -ln(u) with RELATIVE accuracy, u = k ? k*2^-23 : FLT_MIN.
// Fast path uses v_log_f32 (log2).  For u>=15/16 the subtraction 23-log2(k)
// cancels catastrophically (these are the WINNING gumbels), so use a series
// on the exact 1-u instead.
__device__ inline float neglog_u(uint32_t k){
  float L;
  if (k >= 0x780000u){
    float x = (float)(0x800000u - k) * 1.1920928955078125e-7f;   // 1-u, exact
    // -ln(1-x) = x + x^2/2 + x^3/3 + x^4/4, x<=1/16 -> rel err <= 3e-6
    L = x * fmaf(x, fmaf(x, fmaf(x, 0.25f, 0.3333333333333f), 0.5f), 1.0f);
  } else {
    float l2k = __builtin_amdgcn_logf((float)k);                 // log2(k)
    L = 0.69314718055994531f * (23.0f - l2k);
    if (k == 0u) L = 87.33654475055310898f;                      // 126*ln2
  }
  return L;
}

// One threefry call -> gumbel for (t_up, v) AND (t_up+2048, v).  t_up < 2048 so
// m = t_up*V+v < HALF_TV always; counter pair (m, m+HALF) matches JAX's split.
__device__ inline void gumbel_pair(uint32_t kf0, uint32_t kf1, uint32_t t_up, uint32_t v,
                                   float& gu, float& gd){
  uint32_t m = t_up * (uint32_t)VOCAB + v;
  uint32_t x0 = m, x1 = m + HALF_TV;
  tf2x32(kf0, kf1, x0, x1);
  float Lu = neglog_u(x0 >> 9);
  float Ld = neglog_u(x1 >> 9);
  gu = -0.69314718055994531f * __builtin_amdgcn_logf(Lu);
  gd = -0.69314718055994531f * __builtin_amdgcn_logf(Ld);
}

// ---------------- helpers ----------------
__device__ inline unsigned short f2bf(float f){  // RNE f32->bf16
  uint32_t u = __float_as_uint(f);
  return (unsigned short)((u + 0x7FFFu + ((u >> 16) & 1u)) >> 16);
}
__device__ inline float bf2f(unsigned short h){
  return __uint_as_float(((uint32_t)h) << 16);
}
__device__ inline void cvt8(const float* f, bool lo, unsigned short* out){
  #pragma unroll
  for (int e=0;e<8;e++){
    float x = f[e];
    unsigned short h = f2bf(x);
    if (lo) h = f2bf(x - bf2f(h));
    out[e] = h;
  }
}
__device__ inline float blockReduceSum(float v){
  __shared__ float red[4];
  #pragma unroll
  for (int off=32; off>0; off>>=1) v += __shfl_down(v, off);
  int w = threadIdx.x >> 6;
  __syncthreads();
  if ((threadIdx.x & 63) == 0) red[w] = v;
  __syncthreads();
  return red[0] + red[1] + red[2] + red[3];
}

// async global->LDS, 16B per lane (dest must be linear: wave base + lane*16)
__device__ inline void gload16(const void* g, void* l){
  __builtin_amdgcn_global_load_lds(
      (const __attribute__((address_space(1))) unsigned int*)g,
      (__attribute__((address_space(3))) unsigned int*)l, 16, 0, 0);
}

// =====================================================================
// k_hgemm: C[M=4096, N] = A[4096,K] @ Bt[N,K]^T, bf16 inputs, f32 acc.
// Virtual segments for split-bf16: seg0 = Ahi*Bhi, seg1 = Alo*Bhi, seg2 = Ahi*Blo.
// M-tile rows interleave slabs {t, t+2048} at 16-row granularity so the SAMPLE
// epilogue can share one threefry call across the row pair.
// =====================================================================
enum { ST_F32 = 0, ST_HILO = 1, ST_SAMPLE = 2 };

template<int KSTEPS, int NSEG, bool BIAS, bool QGELU, bool RES, int STORE, bool NTST>
__global__ __launch_bounds__(256) void k_hgemm(
    const unsigned short* __restrict__ A0, const unsigned short* __restrict__ A1,
    const unsigned short* __restrict__ B0, const unsigned short* __restrict__ B2,
    float* __restrict__ C, unsigned short* __restrict__ Ch, unsigned short* __restrict__ Cl,
    const float* __restrict__ bias, const float* __restrict__ res,
    int N, uint32_t kf0, uint32_t kf1, unsigned long long* __restrict__ row_best)
{
  constexpr int K = KSTEPS * 64;
  __shared__ unsigned short sA[128*64];
  __shared__ unsigned short sB[128*64];
  const int t = threadIdx.x;
  const int wave = t >> 6, lane = t & 63;
  const int wm = wave >> 1, wn = wave & 1;
  const int g = lane >> 4, r = lane & 15;
  const int lr = lane >> 3, lc = lane & 7;

  // XCD-chunked swizzle: xcd gets bm-pairs [xcd*4, xcd*4+4), bn streams.
  int bid = blockIdx.x;
  int xcd = bid & 7, c = bid >> 3;
  int bm = xcd*4 + (c & 3);
  int bn = c >> 2;

  f32x4 acc[4][4] = {};

  for (int kb = 0; kb < NSEG*KSTEPS; ++kb){
    const int seg = (NSEG == 1) ? 0 : (kb / KSTEPS);
    const int k0  = (NSEG == 1) ? kb*64 : (kb % KSTEPS) * 64;
    const unsigned short* Ap = (seg == 1) ? A1 : A0;
    const unsigned short* Bp = (seg == 2) ? B2 : B0;
    __syncthreads();
    #pragma unroll
    for (int p=0;p<4;p++){
      int mr = p*32 + wave*8 + lr;            // tile-local row; mr&7 == lr
      int blk = mr >> 4;
      int grow = bm*64 + ((blk>>1)<<4) + (mr & 15) + ((blk & 1) ? 2048 : 0);
      int gk = k0 + ((lc ^ lr) << 3);         // pre-swizzled global source chunk
      gload16(Ap + (size_t)grow * K + gk, (char*)sA + mr*128 + lc*16);
      int nrow = bn*128 + mr;
      gload16(Bp + (size_t)nrow * K + gk, (char*)sB + mr*128 + lc*16);
    }
    __syncthreads();
    #pragma unroll
    for (int kk=0;kk<2;kk++){
      bf16x8 av[4], bv[4];
      #pragma unroll
      for (int mi=0;mi<4;mi++){
        int tr = wm*64 + mi*16 + r;
        av[mi] = *(const bf16x8*)((const char*)sA + tr*128 + (((kk*4+g) ^ (r&7))<<4));
      }
      #pragma unroll
      for (int ni=0;ni<4;ni++){
        int tr = wn*64 + ni*16 + r;
        bv[ni] = *(const bf16x8*)((const char*)sB + tr*128 + (((kk*4+g) ^ (r&7))<<4));
      }
      if constexpr (STORE == ST_SAMPLE) __builtin_amdgcn_s_setprio(1);
      #pragma unroll
      for (int mi=0;mi<4;mi++)
        #pragma unroll
        for (int ni=0;ni<4;ni++)
          acc[mi][ni] = __builtin_amdgcn_mfma_f32_16x16x32_bf16(av[mi], bv[ni], acc[mi][ni], 0, 0, 0);
      if constexpr (STORE == ST_SAMPLE) __builtin_amdgcn_s_setprio(0);
    }
  }

  if constexpr (STORE == ST_SAMPLE){
    #pragma unroll
    for (int mi=0; mi<4; mi+=2){
      int row16 = ((wm*4 + mi) >> 1) << 4;
      #pragma unroll
      for (int jj=0;jj<4;jj++){
        uint32_t t_up = bm*64 + row16 + g*4 + jj;   // < 2048
        unsigned long long bu = 0ull, bd = 0ull;
        #pragma unroll
        for (int ni=0;ni<4;ni++){
          uint32_t v = bn*128 + wn*64 + ni*16 + r;
          float gu, gd;
          gumbel_pair(kf0, kf1, t_up, v, gu, gd);
          float vu = acc[mi][ni][jj]   + gu;
          float vd = acc[mi+1][ni][jj] + gd;
          uint32_t fu = __float_as_uint(vu); fu = (fu & 0x80000000u) ? ~fu : (fu | 0x80000000u);
          uint32_t fd = __float_as_uint(vd); fd = (fd & 0x80000000u) ? ~fd : (fd | 0x80000000u);
          unsigned long long pu = ((unsigned long long)fu << 32) | (unsigned long long)(~v);
          unsigned long long pd = ((unsigned long long)fd << 32) | (unsigned long long)(~v);
          if (pu > bu) bu = pu;
          if (pd > bd) bd = pd;
        }
        #pragma unroll
        for (int off=1; off<16; off<<=1){
          unsigned int l0 = (unsigned int)bu, h0 = (unsigned int)(bu>>32);
          unsigned int l1 = __shfl_xor(l0, off), h1 = __shfl_xor(h0, off);
          unsigned long long o = ((unsigned long long)h1 << 32) | (unsigned long long)l1;
          if (o > bu) bu = o;
          l0 = (unsigned int)bd; h0 = (unsigned int)(bd>>32);
          l1 = __shfl_xor(l0, off); h1 = __shfl_xor(h0, off);
          o = ((unsigned long long)h1 << 32) | (unsigned long long)l1;
          if (o > bd) bd = o;
        }
        if (r == 0){
          atomicMax(&row_best[t_up], bu);
          atomicMax(&row_best[t_up + 2048], bd);
        }
      }
    }
  } else {
    #pragma unroll
    for (int mi=0;mi<4;mi++){
      int blk2 = wm*4 + mi;
      int mbase = bm*64 + ((blk2>>1)<<4) + ((blk2 & 1) ? 2048 : 0);
      #pragma unroll
      for (int ni=0;ni<4;ni++){
        int n = bn*128 + wn*64 + ni*16 + r;
        float bv_ = BIAS ? bias[n] : 0.0f;
        #pragma unroll
        for (int jj=0;jj<4;jj++){
          int m = mbase + g*4 + jj;
          float v = acc[mi][ni][jj] + bv_;
          if constexpr (QGELU) v = v / (1.0f + expf(-1.702f * v));
          if constexpr (RES)   v += res[(size_t)m * N + n];
          if constexpr (STORE == ST_F32){
            if constexpr (NTST) __builtin_nontemporal_store(v, &C[(size_t)m * N + n]);
            else                C[(size_t)m * N + n] = v;
          } else {
            unsigned short h = f2bf(v);
            Ch[(size_t)m * N + n] = h;
            Cl[(size_t)m * N + n] = f2bf(v - bf2f(h));
          }
        }
      }
    }
  }
}

// ---------------- weight transpose + f32->bf16 (hi[/lo]) ----------------
// W[K][N] f32  ->  Bt[N][K] bf16 (hi and optionally lo).  NT loads: W is
// single-use; keep L3 for the Bt product + GEMM operands.
template<bool SPLIT>
__global__ __launch_bounds__(256) void k_wt_t(const float* __restrict__ W,
    unsigned short* __restrict__ Bh, unsigned short* __restrict__ Bl, int K, int N)
{
  __shared__ unsigned short sH[64][72];
  __shared__ unsigned short sL[64][72];
  int kt = blockIdx.x, nt = blockIdx.y;
  int t = threadIdx.x;
  int kr = t >> 4, nc4 = (t & 15) * 4;
  #pragma unroll
  for (int p=0;p<4;p++){
    int k = p*16 + kr;
    f32x4v w = __builtin_nontemporal_load((const f32x4v*)&W[(size_t)(kt*64 + k) * N + nt*64 + nc4]);
    #pragma unroll
    for (int e=0;e<4;e++){
      unsigned short h = f2bf(w[e]);
      sH[nc4+e][k] = h;
      if (SPLIT) sL[nc4+e][k] = f2bf(w[e] - bf2f(h));
    }
  }
  __syncthreads();
  #pragma unroll
  for (int q=0;q<2;q++){
    int cid = t + q*256;
    int n = cid >> 3, ch = cid & 7;
    *(bf16x8*)&Bh[(size_t)(nt*64+n)*K + kt*64 + ch*8] = *(const bf16x8*)&sH[n][ch*8];
    if (SPLIT)
      *(bf16x8*)&Bl[(size_t)(nt*64+n)*K + kt*64 + ch*8] = *(const bf16x8*)&sL[n][ch*8];
  }
}

// ---------------- embed + LN (emits bf16 hi/lo of LN output) ----------------
__global__ __launch_bounds__(256) void k_embed_ln(const int* __restrict__ idx,
    const float* __restrict__ wte, const float* __restrict__ g, const float* __restrict__ b,
    float* __restrict__ Xraw, unsigned short* __restrict__ Hh, unsigned short* __restrict__ Hl)
{
  int row = blockIdx.x;
  const float* src = wte + (size_t)idx[row] * DIM;
  float v[3];
  #pragma unroll
  for (int jj=0;jj<3;jj++) v[jj] = src[threadIdx.x + jj*256];
  float s = blockReduceSum(v[0]+v[1]+v[2]);
  float mean = s * (1.0f/DIM);
  float s2 = 0;
  #pragma unroll
  for (int jj=0;jj<3;jj++){ float d = v[jj]-mean; s2 += d*d; }
  s2 = blockReduceSum(s2);
  float rs = rsqrtf(s2 * (1.0f/DIM) + 1e-5f);
  #pragma unroll
  for (int jj=0;jj<3;jj++){
    int d = threadIdx.x + jj*256;
    Xraw[(size_t)row*DIM + d] = v[jj];
    float o = (v[jj]-mean)*rs*g[d] + b[d];
    unsigned short h = f2bf(o);
    Hh[(size_t)row*DIM + d] = h;
    Hl[(size_t)row*DIM + d] = f2bf(o - bf2f(h));
  }
}

// LN: Y -> X (f32) + Xbf (hi) + Xlo
__global__ __launch_bounds__(256) void k_ln(const float* __restrict__ in, float* __restrict__ out,
    const float* __restrict__ g, const float* __restrict__ b,
    unsigned short* __restrict__ obf, unsigned short* __restrict__ olo)
{
  int row = blockIdx.x;
  const float* src = in + (size_t)row * DIM;
  float v[3];
  #pragma unroll
  for (int jj=0;jj<3;jj++) v[jj] = src[threadIdx.x + jj*256];
  float s = blockReduceSum(v[0]+v[1]+v[2]);
  float mean = s * (1.0f/DIM);
  float s2 = 0;
  #pragma unroll
  for (int jj=0;jj<3;jj++){ float d = v[jj]-mean; s2 += d*d; }
  s2 = blockReduceSum(s2);
  float rs = rsqrtf(s2 * (1.0f/DIM) + 1e-5f);
  #pragma unroll
  for (int jj=0;jj<3;jj++){
    int d = threadIdx.x + jj*256;
    float o = (v[jj]-mean)*rs*g[d] + b[d];
    out[(size_t)row*DIM + d] = o;
    unsigned short h = f2bf(o);
    obf[(size_t)row*DIM + d] = h;
    olo[(size_t)row*DIM + d] = f2bf(o - bf2f(h));
  }
}

// ---------------- mask compaction ----------------
__global__ void k_mask(const unsigned long long* __restrict__ row_best,
    const int* __restrict__ idx, int j, int* __restrict__ count, int* __restrict__ plist)
{
  int t = blockIdx.x * blockDim.x + threadIdx.x;
  if (t >= T_TOK) return;
  int v = (int)(~(uint32_t)(row_best[t] & 0xFFFFFFFFull));
  int tgt = (t < T_TOK-1) ? idx[t+1] : -1;
  if (v == tgt && t < T_TOK - j){
    int pos = atomicAdd(count, 1);
    plist[pos] = t;
  }
}

// ---------------- sparse merge MLP (only masked rows) ----------------
__global__ __launch_bounds__(256) void k_merge(const float* __restrict__ X,
    const int* __restrict__ plist, const int* __restrict__ count,
    const float* __restrict__ lng, const float* __restrict__ lnb,
    const float* __restrict__ fcw, const float* __restrict__ fcb,
    const float* __restrict__ pjw, const float* __restrict__ pjb,
    float* __restrict__ mergebuf, int j)
{
  __shared__ float sh[1536 + 3072];
  int nb = *count;
  for (int bIdx = blockIdx.x; bIdx < nb; bIdx += gridDim.x){
    int p = plist[bIdx];
    const float* xp = X + (size_t)p * DIM;
    const float* x2 = X + (size_t)(p + j) * DIM;
    for (int d = threadIdx.x; d < 1536; d += 256)
      sh[d] = (d < DIM) ? xp[d] : x2[d - DIM];
    __syncthreads();
    float s = 0;
    for (int d = threadIdx.x; d < 1536; d += 256) s += sh[d];
    s = blockReduceSum(s);
    float mean = s * (1.0f/1536.0f);
    float s2 = 0;
    for (int d = threadIdx.x; d < 1536; d += 256){ float df = sh[d]-mean; s2 += df*df; }
    s2 = blockReduceSum(s2);
    float rs = rsqrtf(s2 * (1.0f/1536.0f) + 1e-5f);
    __syncthreads();
    for (int d = threadIdx.x; d < 1536; d += 256)
      sh[d] = (sh[d]-mean)*rs*lng[d] + lnb[d];
    __syncthreads();
    float* act = sh + 1536;
    #pragma unroll
    for (int jj=0;jj<12;jj++){
      int n = threadIdx.x + jj*256;
      float a = fcb[n];
      for (int k=0;k<1536;k++) a += sh[k]*fcw[(size_t)k*3072 + n];
      act[n] = a / (1.0f + expf(-1.702f*a));
    }
    __syncthreads();
    #pragma unroll
    for (int jj=0;jj<3;jj++){
      int d = threadIdx.x + jj*256;
      float a = pjb[d];
      for (int k=0;k<3072;k++) a += act[k]*pjw[(size_t)k*DIM + d];
      mergebuf[(size_t)bIdx*DIM + d] = x2[d] + a;
    }
    __syncthreads();
  }
}

__global__ void k_scatter(float* __restrict__ X, unsigned short* __restrict__ Xbf,
    unsigned short* __restrict__ Xlo, const float* __restrict__ mergebuf,
    const int* __restrict__ plist, const int* __restrict__ count, int j)
{
  int nb = *count;
  for (int bIdx = blockIdx.x; bIdx < nb; bIdx += gridDim.x){
    int p = plist[bIdx];
    for (int d = threadIdx.x; d < DIM; d += 256){
      float v = mergebuf[(size_t)bIdx*DIM + d];
      size_t o = (size_t)(p + j)*DIM + d;
      X[o] = v;
      unsigned short h = f2bf(v);
      Xbf[o] = h;
      Xlo[o] = f2bf(v - bf2f(h));
    }
  }
}

// ---------------- fallback final-head GEMM (f32 in, split-bf16, old path) ----
__global__ __launch_bounds__(256) void k_gemm_old(
    const float* __restrict__ A, const float* __restrict__ B, float* __restrict__ C,
    int M, int N, int K)
{
  __shared__ unsigned short sA[128*64];
  __shared__ unsigned short sB[128*64];
  const int t = threadIdx.x;
  const int bn = blockIdx.x, bm = blockIdx.y;
  const int wave = t >> 6, lane = t & 63;
  const int wm = wave >> 1, wn = wave & 1;
  const int g = lane >> 4, r = lane & 15;
  f32x4 acc[4][4] = {};
  const int nK = K >> 6;
  const int aC = t & 7,  aM0 = t >> 3;
  const int bN0 = t & 31, bC = t >> 5;
  const float* Abase = A + (size_t)(bm*128) * K;
  const float* Bbase = B + (size_t)(bn*128);
  for (int seg = 0; seg < 3; ++seg) {
    const bool aLO = (seg == 1), bLO = (seg == 2);
    for (int kb = 0; kb < nK; ++kb) {
      const int k0 = kb << 6;
      __syncthreads();
      #pragma unroll
      for (int p=0;p<4;p++){
        int m = p*32 + aM0;
        const float* src = Abase + (size_t)m * K + k0 + aC*8;
        float ff[8];
        *(float4*)(ff)   = *(const float4*)(src);
        *(float4*)(ff+4) = *(const float4*)(src+4);
        unsigned short hh[8];
        cvt8(ff, aLO, hh);
        *(bf16x8*)&sA[m*64 + ((aC ^ (m & 7)) * 8)] = *(bf16x8*)hh;
      }
      #pragma unroll
      for (int p=0;p<4;p++){
        int n = p*32 + bN0;
        float ff[8];
        const float* src = Bbase + (size_t)(k0 + bC*8) * N + n;
        #pragma unroll
        for (int e=0;e<8;e++) ff[e] = src[(size_t)e * N];
        unsigned short hh[8];
        cvt8(ff, bLO, hh);
        *(bf16x8*)&sB[n*64 + ((bC ^ (n & 7)) * 8)] = *(bf16x8*)hh;
      }
      __syncthreads();
      #pragma unroll
      for (int kk=0;kk<2;kk++){
        bf16x8 av[4], bv[4];
        #pragma unroll
        for (int mi=0;mi<4;mi++){
          int m = wm*64 + mi*16 + r;
          av[mi] = *(const bf16x8*)&sA[m*64 + (((kk*4 + g) ^ (m & 7)) * 8)];
        }
        #pragma unroll
        for (int ni=0;ni<4;ni++){
          int n = wn*64 + ni*16 + r;
          bv[ni] = *(const bf16x8*)&sB[n*64 + (((kk*4 + g) ^ (n & 7)) * 8)];
        }
        #pragma unroll
        for (int mi=0;mi<4;mi++)
          #pragma unroll
          for (int ni=0;ni<4;ni++)
            acc[mi][ni] = __builtin_amdgcn_mfma_f32_16x16x32_bf16(av[mi], bv[ni], acc[mi][ni], 0, 0, 0);
      }
    }
  }
  #pragma unroll
  for (int mi=0;mi<4;mi++)
    #pragma unroll
    for (int ni=0;ni<4;ni++)
      #pragma unroll
      for (int jj=0;jj<4;jj++){
        int m = bm*128 + wm*64 + mi*16 + g*4 + jj;
        int n = bn*128 + wn*64 + ni*16 + r;
        C[(size_t)m * N + n] = acc[mi][ni][jj];
      }
}

// ---------------- host ----------------
static void fold_key(uint32_t i, uint32_t& o0, uint32_t& o1){
  uint32_t x0 = 0, x1 = i;
  tf2x32(0u, 42u, x0, x1);
  o0 = x0; o1 = x1;
}

extern "C" void kernel_launch(void* const* d_in, const int* in_sizes, int n_in,
                              void* d_out, int out_size, void* d_ws, size_t ws_size,
                              hipStream_t stream)
{
  const int*   idx       = (const int*)  d_in[0];
  const float* wte       = (const float*)d_in[1];
  const float* rb_ln_g   = (const float*)d_in[2];
  const float* rb_ln_b   = (const float*)d_in[3];
  const float* rb_fc_w   = (const float*)d_in[4];
  const float* rb_fc_b   = (const float*)d_in[5];
  const float* rb_proj_w = (const float*)d_in[6];
  const float* rb_proj_b = (const float*)d_in[7];
  const float* lnf_g     = (const float*)d_in[8];
  const float* lnf_b     = (const float*)d_in[9];
  const float* lm_head_w = (const float*)d_in[10];
  const float* mb_ln_g   = (const float*)d_in[11];
  const float* mb_ln_b   = (const float*)d_in[12];
  const float* mb_fc_w   = (const float*)d_in[13];
  const float* mb_fc_b   = (const float*)d_in[14];
  const float* mb_proj_w = (const float*)d_in[15];
  const float* mb_proj_b = (const float*)d_in[16];
  const float* op_w      = (const float*)d_in[17];
  const float* op_b      = (const float*)d_in[18];
  const float* lns_g     = (const float*)d_in[19];
  const float* lns_b     = (const float*)d_in[20];
  const float* heads_w   = (const float*)d_in[21];

  const size_t TD = (size_t)T_TOK * DIM;
  const size_t DV = (size_t)DIM * VOCAB;

  // ---- d_ws: X, Y (f32) + Xbf, Xlo (bf16) [+ final-head Bt hi/lo if room]
  float* X = (float*)d_ws;
  float* Y = X + TD;
  unsigned short* Xbf = (unsigned short*)(Y + TD);
  unsigned short* Xlo = Xbf + TD;
  unsigned short* BtFh = Xlo + TD;
  unsigned short* BtFl = BtFh + DV;
  size_t need_big = (size_t)((char*)(BtFl + DV) - (char*)d_ws);
  bool big = ws_size >= need_big;

  // ---- d_out scratch (all consumed before final head GEMM overwrites d_out)
  char* ob = (char*)d_out;
  float* OUT = (float*)d_out;
  unsigned short* Hh     = (unsigned short*)(ob);                 // 2*TD bf16 = 12.6MB
  unsigned short* Hl     = Hh + TD;
  unsigned short* ACTh   = (unsigned short*)(ob + ((size_t)16<<20));  // 25.2MB
  unsigned short* ACTl   = ACTh + TD*4;
  unsigned short* Btfc_h = (unsigned short*)(ob + ((size_t)72<<20));  // [3072][768] x2
  unsigned short* Btfc_l = Btfc_h + (size_t)3072*DIM;
  unsigned short* Btpj_h = (unsigned short*)(ob + ((size_t)84<<20));  // [768][3072] x2
  unsigned short* Btpj_l = Btpj_h + (size_t)3072*DIM;
  unsigned short* BtS    = (unsigned short*)(ob + ((size_t)96<<20));  // [32000][768] 49.2MB
  unsigned short* Btop_h = (unsigned short*)(ob + ((size_t)152<<20)); // [768][768] x2
  unsigned short* Btop_l = Btop_h + (size_t)DIM*DIM;
  float* MERGE = (float*)(ob + ((size_t)160<<20));                    // 12.6MB
  unsigned long long* ROWBEST = (unsigned long long*)(ob + ((size_t)176<<20));
  int* PLIST = (int*)(ROWBEST + T_TOK);
  int* COUNT = PLIST + T_TOK;

  dim3 blk(256);

  // 1) embed + rb_ln -> X (f32), Hh/Hl (bf16 hi/lo)
  k_embed_ln<<<T_TOK, blk, 0, stream>>>(idx, wte, rb_ln_g, rb_ln_b, X, Hh, Hl);
  // 2) weight transposes for prologue MLP
  k_wt_t<true><<<dim3(12,48), blk, 0, stream>>>(rb_fc_w,   Btfc_h, Btfc_l, DIM,  3072);
  k_wt_t<true><<<dim3(48,12), blk, 0, stream>>>(rb_proj_w, Btpj_h, Btpj_l, 3072, DIM);
  // 3) fc (split) + bias + qgelu -> ACT hi/lo
  k_hgemm<12,3,true,true,false,ST_HILO,false><<<24*32, blk, 0, stream>>>(
      Hh, Hl, Btfc_h, Btfc_l, nullptr, ACTh, ACTl, rb_fc_b, nullptr, 3072, 0u,0u, nullptr);
  // 4) proj (split) + bias + residual(X) -> Y
  k_hgemm<48,3,true,false,true,ST_F32,false><<<6*32, blk, 0, stream>>>(
      ACTh, ACTl, Btpj_h, Btpj_l, Y, nullptr, nullptr, rb_proj_b, X, DIM, 0u,0u, nullptr);
  // 5) lnf -> X, Xbf, Xlo
  k_ln<<<T_TOK, blk, 0, stream>>>(Y, X, lnf_g, lnf_b, Xbf, Xlo);

  for (int i = 0; i < NLAYER; ++i){
    int j = i + 1;
    uint32_t kf0, kf1; fold_key((uint32_t)i, kf0, kf1);

    hipMemsetAsync(ROWBEST, 0, (size_t)T_TOK*8, stream);
    hipMemsetAsync(COUNT, 0, 4, stream);

    const float* hw = (i == 0) ? lm_head_w : heads_w + (size_t)(i-1)*DV;
    k_wt_t<false><<<dim3(12,500), blk, 0, stream>>>(hw, BtS, nullptr, DIM, VOCAB);
    // sampling head: bf16 MFMA + fused paired-threefry gumbel-argmax
    k_hgemm<12,1,false,false,false,ST_SAMPLE,false><<<250*32, blk, 0, stream>>>(
        Xbf, Xbf, BtS, BtS, nullptr, nullptr, nullptr, nullptr, nullptr,
        VOCAB, kf0, kf1, ROWBEST);

    k_mask<<<T_TOK/256, blk, 0, stream>>>(ROWBEST, idx, j, COUNT, PLIST);
    k_merge<<<64, blk, 0, stream>>>(X, PLIST, COUNT,
        mb_ln_g + (size_t)i*1536, mb_ln_b + (size_t)i*1536,
        mb_fc_w + (size_t)i*1536*3072, mb_fc_b + (size_t)i*3072,
        mb_proj_w + (size_t)i*3072*DIM, mb_proj_b + (size_t)i*DIM, MERGE, j);
    k_scatter<<<64, blk, 0, stream>>>(X, Xbf, Xlo, MERGE, PLIST, COUNT, j);

    // op (split) + bias -> Y ; then lns -> X, Xbf, Xlo
    k_wt_t<true><<<dim3(12,12), blk, 0, stream>>>(op_w + (size_t)i*DIM*DIM, Btop_h, Btop_l, DIM, DIM);
    k_hgemm<12,3,true,false,false,ST_F32,false><<<6*32, blk, 0, stream>>>(
        Xbf, Xlo, Btop_h, Btop_l, Y, nullptr, nullptr, op_b + (size_t)i*DIM, nullptr,
        DIM, 0u,0u, nullptr);
    k_ln<<<T_TOK, blk, 0, stream>>>(Y, X, lns_g + (size_t)i*DIM, lns_b + (size_t)i*DIM, Xbf, Xlo);
  }

  // final head (split-bf16, f32-grade) -> d_out.  NT stores: the 512MB OUT
  // stream must not evict the 98MB B hi/lo from L3 between segment sweeps.
  if (big){
    k_wt_t<true><<<dim3(12,500), blk, 0, stream>>>(heads_w + (size_t)3*DV, BtFh, BtFl, DIM, VOCAB);
    k_hgemm<12,3,false,false,false,ST_F32,true><<<250*32, blk, 0, stream>>>(
        Xbf, Xlo, BtFh, BtFl, OUT, nullptr, nullptr, nullptr, nullptr, VOCAB, 0u,0u, nullptr);
  } else {
    k_gemm_old<<<dim3(VOCAB/128, T_TOK/128), blk, 0, stream>>>(
        X, heads_w + (size_t)3*DV, OUT, T_TOK, VOCAB, DIM);
  }
}